// Round 5
// baseline (1948.497 us; speedup 1.0000x reference)
//
#include <hip/hip_runtime.h>
#include <math.h>

// LSTM: B=64, T=2048, I=200, H=100. Output h_T [64,100] fp32.
//   prep_kernel : Wt[k][g'] = W_ih[orig(g')][k] fp32 (g'=4q+s interleave, pad 512), bias'
//   prep_whh    : W_hh -> bf16 MFMA A-fragments, permuted gate order, M=512 x K=128
//   xproj_kernel: xg[b,t,g'] = x[b,t,:].Wt[:,g'] + bias'[g']  (fp32 GEMM)
//   lstm_kernel : 64 WGs (one per batch), 256 thr = 4 waves. Per step the matvec
//                 W_hh(512x128)@h is 32 mfma_f32_16x16x32_bf16 per wave (N=1, col 0).
//                 Weights live as MFMA A-frags (AGPR-resident at zero use-cost).
//                 D col0 -> gate dots -> LDS -> 100 updater lanes (fp32 c, xg float4),
//                 bf16 h back to LDS. Two barriers/step.

#define T_TOTAL 2048
#define B_SZ 64
#define IN_SZ 200
#define H_SZ 100
#define GP 512  // padded gate dim

typedef float v2f __attribute__((ext_vector_type(2)));
typedef __attribute__((ext_vector_type(8))) short s8v;   // 8 bf16 = MFMA A/B frag
typedef __attribute__((ext_vector_type(4))) float f4v;   // MFMA C/D frag

__device__ __forceinline__ float sigf(float x) {
    return __builtin_amdgcn_rcpf(1.f + __expf(-x));
}
__device__ __forceinline__ short bf16_rne(float f) {
    unsigned u = __float_as_uint(f);
    u += 0x7FFF + ((u >> 16) & 1);
    return (short)(u >> 16);
}

// ---------------- prep: permuted-transpose W_ih (fp32) + combined bias ----------------
__global__ void prep_kernel(const float* __restrict__ W_ih,
                            const float* __restrict__ b_ih,
                            const float* __restrict__ b_hh,
                            float* __restrict__ Wt,
                            float* __restrict__ bias) {
    int idx = blockIdx.x * 256 + threadIdx.x;
    if (idx < IN_SZ * GP) {
        int k = idx >> 9;
        int gp = idx & (GP - 1);
        int q = gp >> 2, s = gp & 3;          // g' = 4q+s
        int orig = s * H_SZ + q;
        Wt[idx] = (gp < 400) ? W_ih[orig * IN_SZ + k] : 0.f;
    }
    if (idx < GP) {
        int q = idx >> 2, s = idx & 3;
        int orig = s * H_SZ + q;
        bias[idx] = (idx < 400) ? (b_ih[orig] + b_hh[orig]) : 0.f;
    }
}

// ---------------- prep: W_hh -> bf16 A-fragments ----------------
// WA element e = (((w*8+mt)*4+kt)*64 + lane)*8 + j
//   g' = 128w + 16mt + (lane&15) ; k = kt*32 + (lane>>4)*8 + j
//   A[g'][k] = W_hh[(s*100+q)][k] with q=g'>>2, s=g'&3 (zeros in padding)
__global__ void prep_whh(const float* __restrict__ W_hh, short* __restrict__ WA) {
    int e = blockIdx.x * 256 + threadIdx.x;  // 0..65535
    if (e >= 512 * 128) return;
    int j = e & 7;
    int lane = (e >> 3) & 63;
    int kt = (e >> 9) & 3;
    int mt = (e >> 11) & 7;
    int w = e >> 14;
    int gp = 128 * w + 16 * mt + (lane & 15);
    int k = kt * 32 + ((lane >> 4) << 3) + j;
    float val = 0.f;
    if (gp < 400 && k < 100) {
        int q = gp >> 2, s = gp & 3;
        val = W_hh[(s * H_SZ + q) * H_SZ + k];
    }
    WA[e] = bf16_rne(val);
}

// ---------------- input projection GEMM (fp32, pk_fma) ----------------
__global__ __launch_bounds__(256, 4) void xproj_kernel(
    const float* __restrict__ x, const float* __restrict__ Wt,
    const float* __restrict__ bias, float* __restrict__ xg,
    int t0, int Tlen) {
    __shared__ __align__(16) float xTc[50][68];
    __shared__ __align__(16) float4 LW[50][32];

    const int tid = threadIdx.x;
    const int gblk = blockIdx.x;
    const int tbase = t0 + blockIdx.y * 64;
    const int b = blockIdx.z;
    const int gt = tid & 15;
    const int tt = tid >> 4;

    v2f acc[4][4];
#pragma unroll
    for (int r = 0; r < 4; ++r)
#pragma unroll
        for (int h = 0; h < 4; ++h) { acc[r][h].x = 0.f; acc[r][h].y = 0.f; }

    const float2* x2 = (const float2*)x;
    const float4* Wt4 = (const float4*)Wt;

    for (int kc = 0; kc < 4; ++kc) {
        for (int idx = tid; idx < 64 * 25; idx += 256) {
            int row = idx / 25, c2 = idx % 25;
            float2 v = x2[(size_t)(b * T_TOTAL + tbase + row) * (IN_SZ / 2) + kc * 25 + c2];
            xTc[c2 * 2][row] = v.x;
            xTc[c2 * 2 + 1][row] = v.y;
        }
        for (int idx = tid; idx < 50 * 32; idx += 256) {
            int k = idx >> 5, c = idx & 31;
            LW[k][c] = Wt4[(size_t)(kc * 50 + k) * (GP / 4) + gblk * 32 + c];
        }
        __syncthreads();

#pragma unroll 5
        for (int k = 0; k < 50; ++k) {
            float4 xv = *(const float4*)&xTc[k][tt * 4];
            float4 w0 = LW[k][gt];
            float4 w1 = LW[k][16 + gt];
            v2f wv[4];
            wv[0].x = w0.x; wv[0].y = w0.y; wv[1].x = w0.z; wv[1].y = w0.w;
            wv[2].x = w1.x; wv[2].y = w1.y; wv[3].x = w1.z; wv[3].y = w1.w;
            float xa[4] = {xv.x, xv.y, xv.z, xv.w};
#pragma unroll
            for (int tr = 0; tr < 4; ++tr) {
                v2f xs; xs.x = xa[tr]; xs.y = xa[tr];
#pragma unroll
                for (int h = 0; h < 4; ++h)
                    acc[tr][h] = __builtin_elementwise_fma(xs, wv[h], acc[tr][h]);
            }
        }
        __syncthreads();
    }

    const float4* bias4 = (const float4*)bias;
    float4 b0 = bias4[gblk * 32 + gt];
    float4 b1 = bias4[gblk * 32 + 16 + gt];
    float4* o4 = (float4*)xg;
#pragma unroll
    for (int tr = 0; tr < 4; ++tr) {
        int trow = (tbase - t0) + tt * 4 + tr;
        size_t o = (size_t)(b * Tlen + trow) * (GP / 4) + gblk * 32;
        float4 v0 = make_float4(acc[tr][0].x + b0.x, acc[tr][0].y + b0.y,
                                acc[tr][1].x + b0.z, acc[tr][1].y + b0.w);
        float4 v1 = make_float4(acc[tr][2].x + b1.x, acc[tr][2].y + b1.y,
                                acc[tr][3].x + b1.z, acc[tr][3].y + b1.w);
        o4[o + gt] = v0;
        o4[o + 16 + gt] = v1;
    }
}

// ---------------- recurrence: MFMA matvec, one WG (256 thr) per batch ----------------
__global__ __attribute__((amdgpu_flat_work_group_size(256, 256), amdgpu_waves_per_eu(1, 2)))
void lstm_kernel(
    const float* __restrict__ xg, const short* __restrict__ WA,
    float* __restrict__ hstate, float* __restrict__ cstate,
    float* __restrict__ out, int Tlen, int first, int last) {
    __shared__ __align__(16) short hlds[128];   // bf16 h, [100..127] stay 0
    __shared__ __align__(16) float glds[512];   // gate dots, permuted g' order

    const int b = blockIdx.x;
    const int tid = threadIdx.x;
    const int w = tid >> 6;
    const int l = tid & 63;

    // A-fragments: 8 M-tiles x 4 K-tiles, 16B each -> 128 VGPR/AGPR equivalents
    s8v afr[8][4];
    {
        const s8v* WA8 = (const s8v*)WA;
#pragma unroll
        for (int mt = 0; mt < 8; ++mt)
#pragma unroll
            for (int kt = 0; kt < 4; ++kt)
                afr[mt][kt] = WA8[((w * 8 + mt) * 4 + kt) * 64 + l];
    }

    const bool upd = (tid < H_SZ);
    float c = 0.f;
    float hval = 0.f;
    if (upd) c = first ? 0.f : cstate[b * H_SZ + tid];
    if (tid < 128) hlds[tid] = (upd && !first) ? bf16_rne(hstate[b * H_SZ + tid]) : (short)0;
    __syncthreads();

    const f4v* xg4 = (const f4v*)xg;
    const size_t xbase = (size_t)b * Tlen * (GP / 4);
    f4v xa, xb;
#pragma unroll
    for (int i = 0; i < 4; ++i) { xa[i] = 0.f; xb[i] = 0.f; }
    if (upd) {
        xa = xg4[xbase + tid];
        xb = xg4[xbase + (size_t)((Tlen > 1) ? 1 : 0) * (GP / 4) + tid];
    }

    const bool bl = ((l & 15) == 0);      // B-frag / extraction lanes
    const int krow = (l >> 4) << 3;       // 0,8,16,24
    s8v zf;
#pragma unroll
    for (int i = 0; i < 8; ++i) zf[i] = 0;

    for (int tl = 0; tl < Tlen; ++tl) {
        int tpre = tl + 2; if (tpre >= Tlen) tpre = Tlen - 1;
        f4v xn = xb;
        if (upd) xn = xg4[xbase + (size_t)tpre * (GP / 4) + tid];

        // B-fragments: column 0 = h (bf16), rest zero
        s8v bfr[4];
#pragma unroll
        for (int kt = 0; kt < 4; ++kt)
            bfr[kt] = bl ? *(const s8v*)&hlds[kt * 32 + krow] : zf;

        // 8 M-tiles x 4 K accumulations
        f4v acc[8];
#pragma unroll
        for (int mt = 0; mt < 8; ++mt) {
#pragma unroll
            for (int i = 0; i < 4; ++i) acc[mt][i] = 0.f;
#pragma unroll
            for (int kt = 0; kt < 4; ++kt)
                acc[mt] = __builtin_amdgcn_mfma_f32_16x16x32_bf16(afr[mt][kt], bfr[kt], acc[mt], 0, 0, 0);
        }

        // extract col 0: lane 16u holds rows (4u..4u+3) of each tile
        if (bl) {
            int rbase = w * 128 + ((l >> 4) << 2);
#pragma unroll
            for (int mt = 0; mt < 8; ++mt)
                *(f4v*)&glds[rbase + mt * 16] = acc[mt];
        }
        __syncthreads();

        if (upd) {
            f4v gd = *(const f4v*)&glds[4 * tid];
            float gi = gd[0] + xa[0];
            float gf = gd[1] + xa[1];
            float gg = gd[2] + xa[2];
            float go = gd[3] + xa[3];
            float iv = sigf(gi);
            float fv = sigf(gf);
            float gv = __builtin_fmaf(sigf(2.f * gg), 2.f, -1.f);  // tanh
            float ov = sigf(go);
            c = __builtin_fmaf(fv, c, iv * gv);
            float tc = __builtin_fmaf(sigf(2.f * c), 2.f, -1.f);   // tanh(c)
            hval = ov * tc;
            hlds[tid] = bf16_rne(hval);
        }
        __syncthreads();
        xa = xb; xb = xn;
    }

    if (upd) {
        hstate[b * H_SZ + tid] = hval;
        cstate[b * H_SZ + tid] = c;
        if (last) out[b * H_SZ + tid] = hval;
    }
}

// ---------------- host ----------------
extern "C" void kernel_launch(void* const* d_in, const int* in_sizes, int n_in,
                              void* d_out, int out_size, void* d_ws, size_t ws_size,
                              hipStream_t stream) {
    const float* x    = (const float*)d_in[0];
    const float* W_ih = (const float*)d_in[1];
    const float* W_hh = (const float*)d_in[2];
    const float* b_ih = (const float*)d_in[3];
    const float* b_hh = (const float*)d_in[4];
    float* out = (float*)d_out;

    char* ws = (char*)d_ws;
    float* Wt     = (float*)(ws);             // 409600 B
    float* bias   = (float*)(ws + 409600);    // 2048 B
    float* hstate = (float*)(ws + 411648);    // 25600 B
    float* cstate = (float*)(ws + 437248);    // 25600 B
    short* WA     = (short*)(ws + 462848);    // 131072 B
    float* xgbuf  = (float*)(ws + 593920);

    size_t cap = (ws_size > 593920) ? (ws_size - 593920) : 0;
    long long tcmax = (long long)(cap / ((size_t)B_SZ * GP * 4));
    int Tc = (int)((tcmax / 64) * 64);
    if (Tc > T_TOTAL) Tc = T_TOTAL;
    if (Tc < 64) Tc = 64;

    prep_kernel<<<400, 256, 0, stream>>>(W_ih, b_ih, b_hh, Wt, bias);
    prep_whh<<<256, 256, 0, stream>>>(W_hh, WA);

    for (int t0 = 0; t0 < T_TOTAL; t0 += Tc) {
        int Tlen = T_TOTAL - t0;
        if (Tlen > Tc) Tlen = Tc;
        xproj_kernel<<<dim3(4, Tlen / 64, B_SZ), 256, 0, stream>>>(x, Wt, bias, xgbuf, t0, Tlen);
        lstm_kernel<<<B_SZ, 256, 0, stream>>>(xgbuf, WA, hstate, cstate, out,
                                              Tlen, t0 == 0 ? 1 : 0,
                                              (t0 + Tlen) == T_TOTAL ? 1 : 0);
    }
}